// Round 2
// baseline (301.392 us; speedup 1.0000x reference)
//
#include <hip/hip_runtime.h>

#define B_   8192
#define T_   256
#define F_   18
#define U_   32
#define NIDS 1000

typedef float v2f __attribute__((ext_vector_type(2)));

__device__ __forceinline__ float hsig(float x) {
    return fminf(fmaxf(fmaf(x, 0.2f, 0.5f), 0.f), 1.f);
}
__device__ __forceinline__ float ftanh(float x) {
    float e = __expf(2.f * x);
    return 1.f - 2.f * __builtin_amdgcn_rcpf(e + 1.f);
}

// ---------------------------------------------------------------------------
// Phase 1: coalesced float4 scan of the whole input; for each (t,id) keep the
// LAST batch b (atomicMax). Row stride = 18 floats; each float4 contains at
// most one feature-0 element (4*v % 18 == 0 or >= 15).
// ---------------------------------------------------------------------------
#define NTHR (2048 * 256)
__global__ __launch_bounds__(256) void find_winners(
    const float4* __restrict__ in4, int* __restrict__ winner)
{
    int tid = blockIdx.x * 256 + threadIdx.x;
#pragma unroll 2
    for (int it = 0; it < 18; ++it) {
        int v = it * NTHR + tid;
        float4 f = in4[v];
        unsigned e0 = (unsigned)v * 4u;
        unsigned m = e0 % 18u;
        int j = (m == 0u) ? 0 : (m >= 15u ? (int)(18u - m) : -1);
        if (j >= 0) {
            float fv = (j == 0) ? f.x : (j == 1) ? f.y : (j == 2) ? f.z : f.w;
            unsigned row = (e0 + (unsigned)j) / 18u;
            int id = (int)fv;
            id = id < 0 ? 0 : (id > NIDS - 1 ? NIDS - 1 : id);
            atomicMax(&winner[(int)(row & 255u) * NIDS + id], (int)(row >> 8));
        }
    }
}

// ---------------------------------------------------------------------------
// Phase 2 helpers: lane owns unit j of one chain; 2 chains per wave (one per
// 32-lane half). Full h[32] replicated per lane -> z/r dots in-lane; only two
// cross-lane broadcast stages per step (p and h_new).
// ---------------------------------------------------------------------------
__device__ __forceinline__ void loadrow18(float (&xv)[18],
    const float* __restrict__ inputs, int w, int t)
{
    if (w >= 0) {
        const float* p = inputs + ((size_t)w * T_ + t) * F_;
#pragma unroll
        for (int q = 0; q < 18; ++q) xv[q] = p[q];
    } else {
#pragma unroll
        for (int q = 0; q < 18; ++q) xv[q] = 0.f;
    }
}

__device__ __forceinline__ void xdots(const float (&row)[18],
    const v2f (&Kz)[9], const v2f (&Kr)[9], const v2f (&Kh)[9],
    float bz, float br, float bh, float& dz, float& dr, float& dh)
{
    v2f nz = {bz, 0.f}, nr = {br, 0.f}, nh = {bh, 0.f};
#pragma unroll
    for (int q = 0; q < 9; ++q) {
        v2f xq = {row[2*q], row[2*q+1]};
        nz += xq * Kz[q]; nr += xq * Kr[q]; nh += xq * Kh[q];
    }
    dz = nz.x + nz.y; dr = nr.x + nr.y; dh = nh.x + nh.y;
}

// One GRU step. Consumes precomputed x-dots (dz,dr,dh with bias folded in);
// produces next step's x-dots from `row` during the p-broadcast wait.
// Returns new hown; updates replicated h2[].
__device__ __forceinline__ float chain_step(
    v2f (&h2)[16], float hown, float dz, float dr, float dh,
    const v2f (&Uz)[16], const v2f (&Ur)[16], const v2f (&Uh)[16],
    int hbase, bool valid,
    const float (&row)[18],
    const v2f (&Kz)[9], const v2f (&Kr)[9], const v2f (&Kh)[9],
    float bz, float br, float bh,
    float& ndz, float& ndr, float& ndh)
{
    v2f az = {dz, 0.f}, ar = {dr, 0.f};
#pragma unroll
    for (int k = 0; k < 16; ++k) { az += h2[k] * Uz[k]; ar += h2[k] * Ur[k]; }
    float z = hsig(az.x + az.y);
    float r = hsig(ar.x + ar.y);
    float p = r * hown;
    v2f pk[16];
#pragma unroll
    for (int k = 0; k < 16; ++k) {
        pk[k].x = __shfl(p, hbase + 2*k,     64);
        pk[k].y = __shfl(p, hbase + 2*k + 1, 64);
    }
    // filler while p-broadcast is in flight: next step's x-dots
    v2f nz = {bz, 0.f}, nr = {br, 0.f}, nh = {bh, 0.f};
#pragma unroll
    for (int q = 0; q < 9; ++q) {
        v2f xq = {row[2*q], row[2*q+1]};
        nz += xq * Kz[q]; nr += xq * Kr[q]; nh += xq * Kh[q];
    }
    ndz = nz.x + nz.y; ndr = nr.x + nr.y; ndh = nh.x + nh.y;

    v2f ahv = {dh, 0.f};
#pragma unroll
    for (int k = 0; k < 16; ++k) ahv += pk[k] * Uh[k];
    float hh = ftanh(ahv.x + ahv.y);
    float hn = fmaf(z, hown - hh, hh);       // z*h + (1-z)*hh
    hn = valid ? hn : hown;
#pragma unroll
    for (int k = 0; k < 16; ++k) {
        h2[k].x = __shfl(hn, hbase + 2*k,     64);
        h2[k].y = __shfl(hn, hbase + 2*k + 1, 64);
    }
    return hn;
}

// ---------------------------------------------------------------------------
// Phase 2: 1000 chains, 2 per wave, 1 wave per block (512-VGPR budget).
// ---------------------------------------------------------------------------
__global__ __launch_bounds__(64, 1) void run_chains(
    const float* __restrict__ inputs, const float* __restrict__ K,
    const float* __restrict__ R, const float* __restrict__ bias,
    const float* __restrict__ sinit, const int* __restrict__ winner,
    float* __restrict__ table)
{
    __shared__ int wlds[2][256];
    int lane = threadIdx.x;
    int c = lane >> 5;
    int j = lane & 31;
    int hbase = c << 5;
    int chain = blockIdx.x * 2 + c;

    for (int i = lane; i < 512; i += 64) {
        int cc = i & 1, t = i >> 1;
        wlds[cc][t] = (t < T_ - 1) ? winner[t * NIDS + blockIdx.x * 2 + cc] : -1;
    }
    __syncthreads();

    v2f Uz[16], Ur[16], Uh[16];
#pragma unroll
    for (int k = 0; k < 16; ++k) {
        Uz[k] = (v2f){R[(2*k)*96 + j],      R[(2*k+1)*96 + j]};
        Ur[k] = (v2f){R[(2*k)*96 + 32 + j], R[(2*k+1)*96 + 32 + j]};
        Uh[k] = (v2f){R[(2*k)*96 + 64 + j], R[(2*k+1)*96 + 64 + j]};
    }
    v2f Kz[9], Kr[9], Kh[9];
#pragma unroll
    for (int q = 0; q < 9; ++q) {
        Kz[q] = (v2f){K[(2*q)*96 + j],      K[(2*q+1)*96 + j]};
        Kr[q] = (v2f){K[(2*q)*96 + 32 + j], K[(2*q+1)*96 + 32 + j]};
        Kh[q] = (v2f){K[(2*q)*96 + 64 + j], K[(2*q+1)*96 + 64 + j]};
    }
    float bz = bias[j], br = bias[32+j], bh = bias[64+j];

    v2f h2[16];
#pragma unroll
    for (int k = 0; k < 16; ++k)
        h2[k] = (v2f){sinit[chain*U_ + 2*k], sinit[chain*U_ + 2*k + 1]};
    float hown = sinit[chain*U_ + j];

    // pipeline: dots for t, raw rows for t+1 (rowA) and t+2 (rowB)
    float row0[18], rowA[18], rowB[18];
    int w0 = wlds[c][0], wA = wlds[c][1], wB = wlds[c][2];
    loadrow18(row0, inputs, w0, 0);
    loadrow18(rowA, inputs, wA, 1);
    loadrow18(rowB, inputs, wB, 2);
    float dz, dr, dh;
    xdots(row0, Kz, Kr, Kh, bz, br, bh, dz, dr, dh);
    int wcur = w0;

    for (int t = 0; t < 254; t += 2) {
        hown = chain_step(h2, hown, dz, dr, dh, Uz, Ur, Uh, hbase, wcur >= 0,
                          rowA, Kz, Kr, Kh, bz, br, bh, dz, dr, dh);
        wcur = wA;
        int t3 = t + 3;
        wA = wlds[c][t3];
        loadrow18(rowA, inputs, wA, t3);

        hown = chain_step(h2, hown, dz, dr, dh, Uz, Ur, Uh, hbase, wcur >= 0,
                          rowB, Kz, Kr, Kh, bz, br, bh, dz, dr, dh);
        wcur = wB;
        int t4 = t + 4; if (t4 > 255) t4 = 255;
        wB = wlds[c][t4];
        loadrow18(rowB, inputs, wB, t4);
    }
    {   // t = 254 tail
        float u0, u1, u2;
        hown = chain_step(h2, hown, dz, dr, dh, Uz, Ur, Uh, hbase, wcur >= 0,
                          rowA, Kz, Kr, Kh, bz, br, bh, u0, u1, u2);
    }
    table[chain * U_ + j] = hown;   // state entering t=255
}

// ---------------------------------------------------------------------------
// Phase 3 (unchanged from R1, bit-exact path): final step t=255 for all 8192
// batch elements + MLP + sigmoid. kh-split layout.
// ---------------------------------------------------------------------------
__device__ __forceinline__ float fin_gru_step(
    const float (&h)[16], float hown, const float (&xv)[9],
    const float (&Wz)[16], const float (&Wr)[16], const float (&Wh)[16],
    const float (&Kz)[9],  const float (&Kr)[9],  const float (&Kh)[9],
    float bz, float br, float bh, int kh)
{
    float az = 0.f, ar = 0.f;
#pragma unroll
    for (int kk = 0; kk < 16; ++kk) {
        az = fmaf(h[kk], Wz[kk], az);
        ar = fmaf(h[kk], Wr[kk], ar);
    }
#pragma unroll
    for (int q = 0; q < 9; ++q) {
        az = fmaf(xv[q], Kz[q], az);
        ar = fmaf(xv[q], Kr[q], ar);
    }
    az += __shfl_xor(az, 32, 64);
    ar += __shfl_xor(ar, 32, 64);
    float z = hsig(az + bz);
    float r = hsig(ar + br);
    float p = r * hown;
    float ah = 0.f;
#pragma unroll
    for (int kk = 0; kk < 16; ++kk) {
        float pkv = __shfl(p, kh * 16 + kk, 64);
        ah = fmaf(pkv, Wh[kk], ah);
    }
#pragma unroll
    for (int q = 0; q < 9; ++q) ah = fmaf(xv[q], Kh[q], ah);
    ah += __shfl_xor(ah, 32, 64);
    float hh = tanhf(ah + bh);
    return z * hown + (1.f - z) * hh;
}

__global__ __launch_bounds__(256) void finalize(
    const float* __restrict__ inputs, const float* __restrict__ K,
    const float* __restrict__ R, const float* __restrict__ bias,
    const float* __restrict__ table, const float* __restrict__ w1,
    const float* __restrict__ b1, const float* __restrict__ w2,
    const float* __restrict__ b2, float* __restrict__ out)
{
    int tid = threadIdx.x;
    int wv = tid >> 6, lane = tid & 63;
    int j = lane & 31, kh = lane >> 5;

    float Wz[16], Wr[16], Wh[16], w1c[16];
#pragma unroll
    for (int kk = 0; kk < 16; ++kk) {
        int k = kh * 16 + kk;
        Wz[kk]  = R[k * 96 + j];
        Wr[kk]  = R[k * 96 + 32 + j];
        Wh[kk]  = R[k * 96 + 64 + j];
        w1c[kk] = w1[k * 32 + j];
    }
    float Kz[9], Kr[9], Kh[9];
#pragma unroll
    for (int q = 0; q < 9; ++q) {
        int k = kh * 9 + q;
        Kz[q] = K[k * 96 + j];
        Kr[q] = K[k * 96 + 32 + j];
        Kh[q] = K[k * 96 + 64 + j];
    }
    float bz = bias[j], br = bias[32 + j], bh = bias[64 + j];
    float b1v = b1[j], w2v = w2[j], b2v = b2[0];

    int b0 = (blockIdx.x * 4 + wv) * 8;
    for (int bb = 0; bb < 8; ++bb) {
        int b = b0 + bb;
        const float* row = inputs + ((size_t)b * T_ + (T_ - 1)) * F_;
        int id = (int)row[0];
        float xv[9];
#pragma unroll
        for (int q = 0; q < 9; ++q) xv[q] = row[kh * 9 + q];
        float h[16], hown;
#pragma unroll
        for (int kk = 0; kk < 16; ++kk) h[kk] = table[id * U_ + kh * 16 + kk];
        hown = table[id * U_ + j];

        float hn = fin_gru_step(h, hown, xv, Wz, Wr, Wh, Kz, Kr, Kh, bz, br, bh, kh);
        float hrep[16];
#pragma unroll
        for (int kk = 0; kk < 16; ++kk) hrep[kk] = __shfl(hn, kh * 16 + kk, 64);

        float am = 0.f;
#pragma unroll
        for (int kk = 0; kk < 16; ++kk) am = fmaf(hrep[kk], w1c[kk], am);
        am += __shfl_xor(am, 32, 64);
        float hid = fmaxf(am + b1v, 0.f);
        float pr = (kh == 0) ? hid * w2v : 0.f;
#pragma unroll
        for (int s = 1; s < 64; s <<= 1) pr += __shfl_xor(pr, s, 64);
        if (lane == 0) out[b] = 1.f / (1.f + expf(-(pr + b2v)));
    }
}

// ---------------------------------------------------------------------------
extern "C" void kernel_launch(void* const* d_in, const int* in_sizes, int n_in,
                              void* d_out, int out_size, void* d_ws, size_t ws_size,
                              hipStream_t stream)
{
    const float* inputs = (const float*)d_in[0];
    const float* K      = (const float*)d_in[1];
    const float* R      = (const float*)d_in[2];
    const float* bias   = (const float*)d_in[3];
    const float* sinit  = (const float*)d_in[4];
    const float* w1     = (const float*)d_in[5];
    const float* b1     = (const float*)d_in[6];
    const float* w2     = (const float*)d_in[7];
    const float* b2     = (const float*)d_in[8];
    float* out = (float*)d_out;

    int*   winner = (int*)d_ws;                          // 256*1000*4 = 1,024,000 B
    float* table  = (float*)((char*)d_ws + (1 << 20));   // 1000*32*4  = 128,000 B

    hipMemsetAsync(winner, 0xFF, T_ * NIDS * sizeof(int), stream);  // -1
    find_winners<<<dim3(2048), dim3(256), 0, stream>>>((const float4*)inputs, winner);
    run_chains<<<dim3(NIDS / 2), dim3(64), 0, stream>>>(inputs, K, R, bias, sinit, winner, table);
    finalize<<<dim3(B_ / 32), dim3(256), 0, stream>>>(inputs, K, R, bias, table, w1, b1, w2, b2, out);
}

// Round 3
// 198.868 us; speedup vs baseline: 1.5155x; 1.5155x over previous
//
#include <hip/hip_runtime.h>

#define B_   8192
#define T_   256
#define F_   18
#define U_   32
#define NIDS 1000

typedef float v2f __attribute__((ext_vector_type(2)));
typedef float vf4 __attribute__((ext_vector_type(4)));
typedef v2f f2a __attribute__((may_alias));
typedef vf4 f4a __attribute__((may_alias));

#define V2LO(v) __builtin_shufflevector(v, v, 0, 1)
#define V2HI(v) __builtin_shufflevector(v, v, 2, 3)

__device__ __forceinline__ float hsig(float x) {
    return fminf(fmaxf(fmaf(x, 0.2f, 0.5f), 0.f), 1.f);
}
// tanh(x) = 1 - 2/(exp2(2*log2e*x)+1); v_exp_f32 + v_rcp_f32, err ~1e-6
__device__ __forceinline__ float ftanh(float x) {
    float g = __builtin_amdgcn_exp2f(2.885390081777927f * x);
    return 1.f - 2.f * __builtin_amdgcn_rcpf(g + 1.f);
}

// ---------------------------------------------------------------------------
// Phase 1: block t (256 blocks x 1024 thr). LDS atomicMax over the 8192 batch
// rows -> winner[t][id] = last (max) b. No global atomics, no memset needed.
// ---------------------------------------------------------------------------
__global__ __launch_bounds__(1024) void find_winners(
    const float* __restrict__ inputs, int* __restrict__ winner)
{
    __shared__ int loc[NIDS];
    const int tid = threadIdx.x;
    const int t = blockIdx.x;
    for (int i = tid; i < NIDS; i += 1024) loc[i] = -1;
    __syncthreads();

    int ids[8];
#pragma unroll
    for (int u = 0; u < 8; ++u) {
        int b = u * 1024 + tid;
        ids[u] = (int)inputs[(size_t)(b * 256 + t) * F_];
    }
#pragma unroll
    for (int u = 0; u < 8; ++u) {
        int b = u * 1024 + tid;
        int id = ids[u];
        id = id < 0 ? 0 : (id > NIDS - 1 ? NIDS - 1 : id);
        atomicMax(&loc[id], b);
    }
    __syncthreads();
    for (int i = tid; i < NIDS; i += 1024) winner[t * NIDS + i] = loc[i];
}

// ---------------------------------------------------------------------------
// Phase 2 helpers
// ---------------------------------------------------------------------------
__device__ __forceinline__ void loadrow(v2f (&x)[9],
    const float* __restrict__ inputs, int w, int t)
{
    if (w >= 0) {
        const f2a* p = (const f2a*)(inputs + (size_t)(w * T_ + t) * F_);
#pragma unroll
        for (int q = 0; q < 9; ++q) x[q] = p[q];
    } else {
#pragma unroll
        for (int q = 0; q < 9; ++q) x[q] = (v2f){0.f, 0.f};
    }
}

// One GRU step. h comes from LDS (hb4, broadcast reads); p round-trips
// through pslot/pb4. Same-wave DS ops execute in program order -> no barrier.
// Filler (next step's x-dots) sits in the p round-trip latency shadow.
__device__ __forceinline__ float do_step(
    const f4a* __restrict__ hb4, const f4a* __restrict__ pb4,
    float* __restrict__ pslot, float* __restrict__ hslot,
    float hown, float dz, float dr, float dh,
    const v2f (&Uz)[16], const v2f (&Ur)[16], const v2f (&Uh)[16],
    bool valid,
    const v2f (&xrow)[9],
    const v2f (&Kz)[9], const v2f (&Kr)[9], const v2f (&Kh)[9],
    float bz, float br, float bh,
    float& ndz, float& ndr, float& ndh)
{
    v2f az0 = {dz, 0.f}, az1 = {0.f, 0.f};
    v2f ar0 = {dr, 0.f}, ar1 = {0.f, 0.f};
#pragma unroll
    for (int k = 0; k < 8; ++k) {
        vf4 hv = hb4[k];
        v2f lo = V2LO(hv), hi = V2HI(hv);
        az0 += lo * Uz[2*k];  az1 += hi * Uz[2*k+1];
        ar0 += lo * Ur[2*k];  ar1 += hi * Ur[2*k+1];
    }
    float z = hsig(az0.x + az0.y + az1.x + az1.y);
    float r = hsig(ar0.x + ar0.y + ar1.x + ar1.y);
    *pslot = r * hown;                      // ds_write p_j

    // filler while p write->read is in flight: next step's x-dots
    v2f nz = {bz, 0.f}, nr = {br, 0.f}, nh = {bh, 0.f};
#pragma unroll
    for (int q = 0; q < 9; ++q) {
        nz += xrow[q] * Kz[q]; nr += xrow[q] * Kr[q]; nh += xrow[q] * Kh[q];
    }
    ndz = nz.x + nz.y; ndr = nr.x + nr.y; ndh = nh.x + nh.y;

    v2f ah0 = {dh, 0.f}, ah1 = {0.f, 0.f};
#pragma unroll
    for (int k = 0; k < 8; ++k) {
        vf4 pv = pb4[k];                    // broadcast reads (no conflict)
        ah0 += V2LO(pv) * Uh[2*k];  ah1 += V2HI(pv) * Uh[2*k+1];
    }
    float hh = ftanh(ah0.x + ah0.y + ah1.x + ah1.y);
    float hn = fmaf(z, hown - hh, hh);      // z*h + (1-z)*hh
    hn = valid ? hn : hown;
    *hslot = hn;                            // ds_write h_j for next step
    return hn;
}

// ---------------------------------------------------------------------------
// Phase 2: 1000 chains, 2 per wave, 1 wave per block.
// ---------------------------------------------------------------------------
__global__ __launch_bounds__(64, 1) void run_chains(
    const float* __restrict__ inputs, const float* __restrict__ K,
    const float* __restrict__ R, const float* __restrict__ bias,
    const float* __restrict__ sinit, const int* __restrict__ winner,
    float* __restrict__ table)
{
    __shared__ int wlds[2][256];
    __shared__ alignas(16) float pbuf[2][32];
    __shared__ alignas(16) float hbuf[2][32];

    const int lane = threadIdx.x;
    const int c = lane >> 5, j = lane & 31;
    const int chain = blockIdx.x * 2 + c;

    // stage winner column (single wave: in-order DS, no barrier needed)
#pragma unroll
    for (int i = 0; i < 8; ++i) {
        int idx = i * 64 + lane;
        int cc = idx >> 8, t = idx & 255;
        wlds[cc][t] = (t < T_ - 1) ? winner[t * NIDS + blockIdx.x * 2 + cc] : -1;
    }
    float hinit = sinit[chain * U_ + j];
    hbuf[c][j] = hinit;
    float hown = hinit;

    v2f Uz[16], Ur[16], Uh[16];
#pragma unroll
    for (int k = 0; k < 16; ++k) {
        Uz[k] = (v2f){R[(2*k)*96 + j],      R[(2*k+1)*96 + j]};
        Ur[k] = (v2f){R[(2*k)*96 + 32 + j], R[(2*k+1)*96 + 32 + j]};
        Uh[k] = (v2f){R[(2*k)*96 + 64 + j], R[(2*k+1)*96 + 64 + j]};
    }
    v2f Kz[9], Kr[9], Kh[9];
#pragma unroll
    for (int q = 0; q < 9; ++q) {
        Kz[q] = (v2f){K[(2*q)*96 + j],      K[(2*q+1)*96 + j]};
        Kr[q] = (v2f){K[(2*q)*96 + 32 + j], K[(2*q+1)*96 + 32 + j]};
        Kh[q] = (v2f){K[(2*q)*96 + 64 + j], K[(2*q+1)*96 + 64 + j]};
    }
    const float bz = bias[j], br = bias[32 + j], bh = bias[64 + j];

    const f4a* hb4 = (const f4a*)hbuf[c];
    const f4a* pb4 = (const f4a*)pbuf[c];
    float* pslot = &pbuf[c][j];
    float* hslot = &hbuf[c][j];

    // pipeline: dots for t=0; raw rows t+1..t+3 in A,B,C (prefetch depth 3)
    v2f row0[9], rowA[9], rowB[9], rowC[9];
    int w0 = wlds[c][0], wA = wlds[c][1], wB = wlds[c][2], wC = wlds[c][3];
    loadrow(row0, inputs, w0, 0);
    loadrow(rowA, inputs, wA, 1);
    loadrow(rowB, inputs, wB, 2);
    loadrow(rowC, inputs, wC, 3);

    float dz, dr, dh;
    {
        v2f nz = {bz, 0.f}, nr = {br, 0.f}, nh = {bh, 0.f};
#pragma unroll
        for (int q = 0; q < 9; ++q) {
            nz += row0[q] * Kz[q]; nr += row0[q] * Kr[q]; nh += row0[q] * Kh[q];
        }
        dz = nz.x + nz.y; dr = nr.x + nr.y; dh = nh.x + nh.y;
    }
    int wcur = w0;

    for (int t = 0; t < 255; t += 3) {   // 85 iterations x 3 steps
        hown = do_step(hb4, pb4, pslot, hslot, hown, dz, dr, dh,
                       Uz, Ur, Uh, wcur >= 0, rowA, Kz, Kr, Kh,
                       bz, br, bh, dz, dr, dh);
        wcur = wA;
        { int tt = t + 4; tt = tt > 255 ? 255 : tt;
          wA = wlds[c][tt]; loadrow(rowA, inputs, wA, tt); }

        hown = do_step(hb4, pb4, pslot, hslot, hown, dz, dr, dh,
                       Uz, Ur, Uh, wcur >= 0, rowB, Kz, Kr, Kh,
                       bz, br, bh, dz, dr, dh);
        wcur = wB;
        { int tt = t + 5; tt = tt > 255 ? 255 : tt;
          wB = wlds[c][tt]; loadrow(rowB, inputs, wB, tt); }

        hown = do_step(hb4, pb4, pslot, hslot, hown, dz, dr, dh,
                       Uz, Ur, Uh, wcur >= 0, rowC, Kz, Kr, Kh,
                       bz, br, bh, dz, dr, dh);
        wcur = wC;
        { int tt = t + 6; tt = tt > 255 ? 255 : tt;
          wC = wlds[c][tt]; loadrow(rowC, inputs, wC, tt); }
    }

    table[chain * U_ + j] = hown;   // state entering t=255
}

// ---------------------------------------------------------------------------
// Phase 3: final step t=255 for all 8192 batch elements + MLP + sigmoid.
// ---------------------------------------------------------------------------
__device__ __forceinline__ float fin_gru_step(
    const float (&h)[16], float hown, const float (&xv)[9],
    const float (&Wz)[16], const float (&Wr)[16], const float (&Wh)[16],
    const float (&Kz)[9],  const float (&Kr)[9],  const float (&Kh)[9],
    float bz, float br, float bh, int kh)
{
    float az = 0.f, ar = 0.f;
#pragma unroll
    for (int kk = 0; kk < 16; ++kk) {
        az = fmaf(h[kk], Wz[kk], az);
        ar = fmaf(h[kk], Wr[kk], ar);
    }
#pragma unroll
    for (int q = 0; q < 9; ++q) {
        az = fmaf(xv[q], Kz[q], az);
        ar = fmaf(xv[q], Kr[q], ar);
    }
    az += __shfl_xor(az, 32, 64);
    ar += __shfl_xor(ar, 32, 64);
    float z = hsig(az + bz);
    float r = hsig(ar + br);
    float p = r * hown;
    float ah = 0.f;
#pragma unroll
    for (int kk = 0; kk < 16; ++kk) {
        float pkv = __shfl(p, kh * 16 + kk, 64);
        ah = fmaf(pkv, Wh[kk], ah);
    }
#pragma unroll
    for (int q = 0; q < 9; ++q) ah = fmaf(xv[q], Kh[q], ah);
    ah += __shfl_xor(ah, 32, 64);
    float hh = tanhf(ah + bh);
    return z * hown + (1.f - z) * hh;
}

__global__ __launch_bounds__(256) void finalize(
    const float* __restrict__ inputs, const float* __restrict__ K,
    const float* __restrict__ R, const float* __restrict__ bias,
    const float* __restrict__ table, const float* __restrict__ w1,
    const float* __restrict__ b1, const float* __restrict__ w2,
    const float* __restrict__ b2, float* __restrict__ out)
{
    int tid = threadIdx.x;
    int wv = tid >> 6, lane = tid & 63;
    int j = lane & 31, kh = lane >> 5;

    float Wz[16], Wr[16], Wh[16], w1c[16];
#pragma unroll
    for (int kk = 0; kk < 16; ++kk) {
        int k = kh * 16 + kk;
        Wz[kk]  = R[k * 96 + j];
        Wr[kk]  = R[k * 96 + 32 + j];
        Wh[kk]  = R[k * 96 + 64 + j];
        w1c[kk] = w1[k * 32 + j];
    }
    float Kz[9], Kr[9], Kh[9];
#pragma unroll
    for (int q = 0; q < 9; ++q) {
        int k = kh * 9 + q;
        Kz[q] = K[k * 96 + j];
        Kr[q] = K[k * 96 + 32 + j];
        Kh[q] = K[k * 96 + 64 + j];
    }
    float bz = bias[j], br = bias[32 + j], bh = bias[64 + j];
    float b1v = b1[j], w2v = w2[j], b2v = b2[0];

    int b0 = (blockIdx.x * 4 + wv) * 8;
    for (int bb = 0; bb < 8; ++bb) {
        int b = b0 + bb;
        const float* row = inputs + ((size_t)b * T_ + (T_ - 1)) * F_;
        int id = (int)row[0];
        float xv[9];
#pragma unroll
        for (int q = 0; q < 9; ++q) xv[q] = row[kh * 9 + q];
        float h[16], hown;
#pragma unroll
        for (int kk = 0; kk < 16; ++kk) h[kk] = table[id * U_ + kh * 16 + kk];
        hown = table[id * U_ + j];

        float hn = fin_gru_step(h, hown, xv, Wz, Wr, Wh, Kz, Kr, Kh, bz, br, bh, kh);
        float hrep[16];
#pragma unroll
        for (int kk = 0; kk < 16; ++kk) hrep[kk] = __shfl(hn, kh * 16 + kk, 64);

        float am = 0.f;
#pragma unroll
        for (int kk = 0; kk < 16; ++kk) am = fmaf(hrep[kk], w1c[kk], am);
        am += __shfl_xor(am, 32, 64);
        float hid = fmaxf(am + b1v, 0.f);
        float pr = (kh == 0) ? hid * w2v : 0.f;
#pragma unroll
        for (int s = 1; s < 64; s <<= 1) pr += __shfl_xor(pr, s, 64);
        if (lane == 0) out[b] = 1.f / (1.f + expf(-(pr + b2v)));
    }
}

// ---------------------------------------------------------------------------
extern "C" void kernel_launch(void* const* d_in, const int* in_sizes, int n_in,
                              void* d_out, int out_size, void* d_ws, size_t ws_size,
                              hipStream_t stream)
{
    const float* inputs = (const float*)d_in[0];
    const float* K      = (const float*)d_in[1];
    const float* R      = (const float*)d_in[2];
    const float* bias   = (const float*)d_in[3];
    const float* sinit  = (const float*)d_in[4];
    const float* w1     = (const float*)d_in[5];
    const float* b1     = (const float*)d_in[6];
    const float* w2     = (const float*)d_in[7];
    const float* b2     = (const float*)d_in[8];
    float* out = (float*)d_out;

    int*   winner = (int*)d_ws;                          // 256*1000*4 = 1,024,000 B
    float* table  = (float*)((char*)d_ws + (1 << 20));   // 1000*32*4  = 128,000 B

    find_winners<<<dim3(T_), dim3(1024), 0, stream>>>(inputs, winner);
    run_chains<<<dim3(NIDS / 2), dim3(64), 0, stream>>>(inputs, K, R, bias, sinit, winner, table);
    finalize<<<dim3(B_ / 32), dim3(256), 0, stream>>>(inputs, K, R, bias, table, w1, b1, w2, b2, out);
}

// Round 4
// 172.246 us; speedup vs baseline: 1.7498x; 1.1546x over previous
//
#include <hip/hip_runtime.h>

#define B_   8192
#define T_   256
#define F_   18
#define U_   32
#define NIDS 1000

typedef float v2f  __attribute__((ext_vector_type(2)));
typedef float vf4  __attribute__((ext_vector_type(4)));
typedef v2f  f2a   __attribute__((may_alias));
typedef vf4  f4a   __attribute__((may_alias));
typedef float uf4  __attribute__((ext_vector_type(4), aligned(4), may_alias));
typedef float uf2  __attribute__((ext_vector_type(2), aligned(4), may_alias));

#define V2LO(v) __builtin_shufflevector(v, v, 0, 1)
#define V2HI(v) __builtin_shufflevector(v, v, 2, 3)

__device__ __forceinline__ float hsig(float x) {
    return fminf(fmaxf(fmaf(x, 0.2f, 0.5f), 0.f), 1.f);
}
__device__ __forceinline__ float ftanh(float x) {
    float g = __builtin_amdgcn_exp2f(2.885390081777927f * x);
    return 1.f - 2.f * __builtin_amdgcn_rcpf(g + 1.f);
}

// ---------------------------------------------------------------------------
// Phase 1: block owns 32 consecutive batch rows (contiguous 576KB slab).
// Fully-coalesced float4 stream; ids sit at element positions 18*m (even), so
// within a float4 only lanes .x (4v%18==0) or .z (4v%18==16) can be ids.
// ---------------------------------------------------------------------------
__global__ __launch_bounds__(1024) void find_winners(
    const float4* __restrict__ in4, int* __restrict__ winner)
{
    const int tid = threadIdx.x;
    const int blk = blockIdx.x;
    const int base = blk * 36864;            // float4s per block (32*256*18/4)
#pragma unroll
    for (int k = 0; k < 36; ++k) {
        int v = k * 1024 + tid;              // block-local float4 index
        float4 f = in4[base + v];
        unsigned e0 = (unsigned)v * 4u;
        unsigned rem = e0 % 18u;
        int j = (rem == 0u) ? 0 : (rem == 16u ? 2 : -1);
        if (j >= 0) {
            float fv = (j == 0) ? f.x : f.z;
            unsigned m = (e0 + (unsigned)j) / 18u;   // local (b,t) ordinal
            int t = (int)(m & 255u);
            int b = blk * 32 + (int)(m >> 8);
            int id = (int)fv;
            id = id < 0 ? 0 : (id > NIDS - 1 ? NIDS - 1 : id);
            atomicMax(&winner[t * NIDS + id], b);
        }
    }
}

// ---------------------------------------------------------------------------
// Phase 2: one GRU step. h and p broadcast through LDS (same-wave DS ops are
// in-order -> no barriers). x-row + validity sentinel come from the chunked
// LDS buffer; the next step's x-dots are computed in the p round-trip shadow.
// Sentinel: vmask=1e6 added to dz -> z==1 -> h_new == h (skipped step).
// ---------------------------------------------------------------------------
__device__ __forceinline__ float do_step(
    const f4a* __restrict__ hb4, const f4a* __restrict__ pb4,
    float* __restrict__ pslot, float* __restrict__ hslot,
    float hown, float& dz, float& dr, float& dh,
    const v2f (&Uz)[16], const v2f (&Ur)[16], const v2f (&Uh)[16],
    const float* __restrict__ xnext,
    const v2f (&Kz)[9], const v2f (&Kr)[9], const v2f (&Kh)[9],
    float bz, float br, float bh)
{
    const float dhc = dh;
    v2f az0 = {dz, 0.f}, az1 = {0.f, 0.f};
    v2f ar0 = {dr, 0.f}, ar1 = {0.f, 0.f};
#pragma unroll
    for (int k = 0; k < 8; ++k) {
        vf4 hv = hb4[k];
        v2f lo = V2LO(hv), hi = V2HI(hv);
        az0 += lo * Uz[2*k];  az1 += hi * Uz[2*k+1];
        ar0 += lo * Ur[2*k];  ar1 += hi * Ur[2*k+1];
    }
    float z = hsig(az0.x + az0.y + az1.x + az1.y);
    float r = hsig(ar0.x + ar0.y + ar1.x + ar1.y);
    *pslot = r * hown;                       // ds_write p_j

    // filler while p write->read round-trips: next step's x-dots from LDS
    const f4a* xp = (const f4a*)xnext;
    vf4 x0 = xp[0], x1 = xp[1], x2 = xp[2], x3 = xp[3];
    v2f x4 = *(const f2a*)(xnext + 16);
    float vm = xnext[18];
    v2f nz = {bz, 0.f}, nr = {br, 0.f}, nh = {bh, 0.f};
    v2f xq[9] = {V2LO(x0), V2HI(x0), V2LO(x1), V2HI(x1),
                 V2LO(x2), V2HI(x2), V2LO(x3), V2HI(x3), x4};
#pragma unroll
    for (int q = 0; q < 9; ++q) {
        nz += xq[q] * Kz[q]; nr += xq[q] * Kr[q]; nh += xq[q] * Kh[q];
    }
    dz = nz.x + nz.y + vm; dr = nr.x + nr.y; dh = nh.x + nh.y;

    v2f ah0 = {dhc, 0.f}, ah1 = {0.f, 0.f};
#pragma unroll
    for (int k = 0; k < 8; ++k) {
        vf4 pv = pb4[k];
        ah0 += V2LO(pv) * Uh[2*k];  ah1 += V2HI(pv) * Uh[2*k+1];
    }
    float hh = ftanh(ah0.x + ah0.y + ah1.x + ah1.y);
    float hn = fmaf(z, hown - hh, hh);
    *hslot = hn;                             // ds_write h_j for next step
    return hn;
}

// ---------------------------------------------------------------------------
// Phase 2: 1000 chains, 2/wave, 1 wave/block. 16 chunks x 16 steps (t=255 is
// an automatic no-op via the sentinel). X-rows staged chunk-wise into LDS,
// double-buffered, loads issued one full chunk ahead (~16 steps ~ 6000cy).
// ---------------------------------------------------------------------------
__global__ __launch_bounds__(64, 1) void run_chains(
    const float* __restrict__ inputs, const float* __restrict__ K,
    const float* __restrict__ R, const float* __restrict__ bias,
    const float* __restrict__ sinit, const int* __restrict__ winner,
    float* __restrict__ table)
{
    __shared__ int wlds[2][256];
    __shared__ alignas(16) float xbuf[2][2][16][20];  // [buf][chain][row][18x+vm+pad]
    __shared__ alignas(16) float pbuf[2][32];
    __shared__ alignas(16) float hbuf[2][32];

    const int lane = threadIdx.x;
    const int c = lane >> 5, j = lane & 31;
    const int chain = blockIdx.x * 2 + c;

    // winner columns -> LDS (single wave: in-order DS, no barrier)
#pragma unroll
    for (int i = 0; i < 8; ++i) {
        int idx = i * 64 + lane;
        int cc = idx >> 8, t = idx & 255;
        wlds[cc][t] = (t < T_ - 1) ? winner[t * NIDS + blockIdx.x * 2 + cc] : -1;
    }
    float hinit = sinit[chain * U_ + j];
    hbuf[c][j] = hinit;
    float hown = hinit;

    v2f Uz[16], Ur[16], Uh[16];
#pragma unroll
    for (int k = 0; k < 16; ++k) {
        Uz[k] = (v2f){R[(2*k)*96 + j],      R[(2*k+1)*96 + j]};
        Ur[k] = (v2f){R[(2*k)*96 + 32 + j], R[(2*k+1)*96 + 32 + j]};
        Uh[k] = (v2f){R[(2*k)*96 + 64 + j], R[(2*k+1)*96 + 64 + j]};
    }
    v2f Kz[9], Kr[9], Kh[9];
#pragma unroll
    for (int q = 0; q < 9; ++q) {
        Kz[q] = (v2f){K[(2*q)*96 + j],      K[(2*q+1)*96 + j]};
        Kr[q] = (v2f){K[(2*q)*96 + 32 + j], K[(2*q+1)*96 + 32 + j]};
        Kh[q] = (v2f){K[(2*q)*96 + 64 + j], K[(2*q+1)*96 + 64 + j]};
    }
    const float bz = bias[j], br = bias[32 + j], bh = bias[64 + j];

    // staging role: 2 lanes per row; 32 rows = 2 chains x 16 steps
    const int rr = lane >> 1, pp = lane & 1;
    const int scc = rr >> 4, sidx = rr & 15;

    uf4 r0, r1; uf2 r2; float vmk = 0.f;

    // ---- stage chunk into regs (for chunk ck) ----
    auto issue_loads = [&](int ck) {
        int tt = ck * 16 + sidx;
        int w = wlds[scc][tt];
        vmk = (w < 0) ? 1e6f : 0.f;
        int wc = w < 0 ? 0 : w;
        const float* src = inputs + (size_t)(wc * 256 + tt) * 18;
        if (pp == 0) { r0 = *(const uf4*)(src);      r1 = *(const uf4*)(src + 4); }
        else         { r0 = *(const uf4*)(src + 8);  r1 = *(const uf4*)(src + 12);
                       r2 = *(const uf2*)(src + 16); }
    };
    // ---- write staged regs into buffer nb ----
    auto write_buf = [&](int nb) {
        float* dst = &xbuf[nb][scc][sidx][0];
        if (pp == 0) { *(f4a*)(dst)      = (vf4)r0; *(f4a*)(dst + 4)  = (vf4)r1; }
        else         { *(f4a*)(dst + 8)  = (vf4)r0; *(f4a*)(dst + 12) = (vf4)r1;
                       *(f2a*)(dst + 16) = (v2f)r2; dst[18] = vmk; }
    };

    // prologue: chunk0 -> buf0; chunk1 loads left in flight
    issue_loads(0);
    write_buf(0);
    issue_loads(1);

    // initial dots for t=0 from buf0 row0
    float dz, dr, dh;
    {
        const float* x = &xbuf[0][c][0][0];
        const f4a* xp = (const f4a*)x;
        vf4 x0 = xp[0], x1 = xp[1], x2 = xp[2], x3 = xp[3];
        v2f x4 = *(const f2a*)(x + 16);
        float vm = x[18];
        v2f xq[9] = {V2LO(x0), V2HI(x0), V2LO(x1), V2HI(x1),
                     V2LO(x2), V2HI(x2), V2LO(x3), V2HI(x3), x4};
        v2f nz = {bz, 0.f}, nr = {br, 0.f}, nh = {bh, 0.f};
#pragma unroll
        for (int q = 0; q < 9; ++q) {
            nz += xq[q] * Kz[q]; nr += xq[q] * Kr[q]; nh += xq[q] * Kh[q];
        }
        dz = nz.x + nz.y + vm; dr = nr.x + nr.y; dh = nh.x + nh.y;
    }

    const f4a* hb4 = (const f4a*)hbuf[c];
    const f4a* pb4 = (const f4a*)pbuf[c];
    float* pslot = &pbuf[c][j];
    float* hslot = &hbuf[c][j];

    for (int i = 0; i < 16; ++i) {
        const float* bufc  = &xbuf[i & 1][c][0][0];
        const float* nbufc = &xbuf[(i + 1) & 1][c][0][0];
        for (int s = 0; s < 15; ++s) {       // steps t = 16i .. 16i+14
            hown = do_step(hb4, pb4, pslot, hslot, hown, dz, dr, dh,
                           Uz, Ur, Uh, bufc + (s + 1) * 20,
                           Kz, Kr, Kh, bz, br, bh);
        }
        if (i < 15) {
            write_buf((i + 1) & 1);          // implicit vmcnt wait (chunk-old)
            if (i < 14) issue_loads(i + 2);
        }
        // step t = 16i+15; its filler reads row0 of the next buffer
        hown = do_step(hb4, pb4, pslot, hslot, hown, dz, dr, dh,
                       Uz, Ur, Uh, nbufc,
                       Kz, Kr, Kh, bz, br, bh);
    }

    table[chain * U_ + j] = hown;            // state entering t=255 (t=255 was a no-op)
}

// ---------------------------------------------------------------------------
// Phase 3: final step t=255 for all 8192 batch elements + MLP + sigmoid.
// ---------------------------------------------------------------------------
__device__ __forceinline__ float fin_gru_step(
    const float (&h)[16], float hown, const float (&xv)[9],
    const float (&Wz)[16], const float (&Wr)[16], const float (&Wh)[16],
    const float (&Kz)[9],  const float (&Kr)[9],  const float (&Kh)[9],
    float bz, float br, float bh, int kh)
{
    float az = 0.f, ar = 0.f;
#pragma unroll
    for (int kk = 0; kk < 16; ++kk) {
        az = fmaf(h[kk], Wz[kk], az);
        ar = fmaf(h[kk], Wr[kk], ar);
    }
#pragma unroll
    for (int q = 0; q < 9; ++q) {
        az = fmaf(xv[q], Kz[q], az);
        ar = fmaf(xv[q], Kr[q], ar);
    }
    az += __shfl_xor(az, 32, 64);
    ar += __shfl_xor(ar, 32, 64);
    float z = hsig(az + bz);
    float r = hsig(ar + br);
    float p = r * hown;
    float ah = 0.f;
#pragma unroll
    for (int kk = 0; kk < 16; ++kk) {
        float pkv = __shfl(p, kh * 16 + kk, 64);
        ah = fmaf(pkv, Wh[kk], ah);
    }
#pragma unroll
    for (int q = 0; q < 9; ++q) ah = fmaf(xv[q], Kh[q], ah);
    ah += __shfl_xor(ah, 32, 64);
    float hh = tanhf(ah + bh);
    return z * hown + (1.f - z) * hh;
}

__global__ __launch_bounds__(256) void finalize(
    const float* __restrict__ inputs, const float* __restrict__ K,
    const float* __restrict__ R, const float* __restrict__ bias,
    const float* __restrict__ table, const float* __restrict__ w1,
    const float* __restrict__ b1, const float* __restrict__ w2,
    const float* __restrict__ b2, float* __restrict__ out)
{
    int tid = threadIdx.x;
    int wv = tid >> 6, lane = tid & 63;
    int j = lane & 31, kh = lane >> 5;

    float Wz[16], Wr[16], Wh[16], w1c[16];
#pragma unroll
    for (int kk = 0; kk < 16; ++kk) {
        int k = kh * 16 + kk;
        Wz[kk]  = R[k * 96 + j];
        Wr[kk]  = R[k * 96 + 32 + j];
        Wh[kk]  = R[k * 96 + 64 + j];
        w1c[kk] = w1[k * 32 + j];
    }
    float Kz[9], Kr[9], Kh[9];
#pragma unroll
    for (int q = 0; q < 9; ++q) {
        int k = kh * 9 + q;
        Kz[q] = K[k * 96 + j];
        Kr[q] = K[k * 96 + 32 + j];
        Kh[q] = K[k * 96 + 64 + j];
    }
    float bz = bias[j], br = bias[32 + j], bh = bias[64 + j];
    float b1v = b1[j], w2v = w2[j], b2v = b2[0];

    int b0 = (blockIdx.x * 4 + wv) * 8;
    for (int bb = 0; bb < 8; ++bb) {
        int b = b0 + bb;
        const float* row = inputs + ((size_t)b * T_ + (T_ - 1)) * F_;
        int id = (int)row[0];
        float xv[9];
#pragma unroll
        for (int q = 0; q < 9; ++q) xv[q] = row[kh * 9 + q];
        float h[16], hown;
#pragma unroll
        for (int kk = 0; kk < 16; ++kk) h[kk] = table[id * U_ + kh * 16 + kk];
        hown = table[id * U_ + j];

        float hn = fin_gru_step(h, hown, xv, Wz, Wr, Wh, Kz, Kr, Kh, bz, br, bh, kh);
        float hrep[16];
#pragma unroll
        for (int kk = 0; kk < 16; ++kk) hrep[kk] = __shfl(hn, kh * 16 + kk, 64);

        float am = 0.f;
#pragma unroll
        for (int kk = 0; kk < 16; ++kk) am = fmaf(hrep[kk], w1c[kk], am);
        am += __shfl_xor(am, 32, 64);
        float hid = fmaxf(am + b1v, 0.f);
        float pr = (kh == 0) ? hid * w2v : 0.f;
#pragma unroll
        for (int s = 1; s < 64; s <<= 1) pr += __shfl_xor(pr, s, 64);
        if (lane == 0) out[b] = 1.f / (1.f + expf(-(pr + b2v)));
    }
}

// ---------------------------------------------------------------------------
extern "C" void kernel_launch(void* const* d_in, const int* in_sizes, int n_in,
                              void* d_out, int out_size, void* d_ws, size_t ws_size,
                              hipStream_t stream)
{
    const float* inputs = (const float*)d_in[0];
    const float* K      = (const float*)d_in[1];
    const float* R      = (const float*)d_in[2];
    const float* bias   = (const float*)d_in[3];
    const float* sinit  = (const float*)d_in[4];
    const float* w1     = (const float*)d_in[5];
    const float* b1     = (const float*)d_in[6];
    const float* w2     = (const float*)d_in[7];
    const float* b2     = (const float*)d_in[8];
    float* out = (float*)d_out;

    int*   winner = (int*)d_ws;                          // 256*1000*4 = 1,024,000 B
    float* table  = (float*)((char*)d_ws + (1 << 20));   // 1000*32*4  = 128,000 B

    hipMemsetAsync(winner, 0xFF, T_ * NIDS * sizeof(int), stream);  // -1
    find_winners<<<dim3(256), dim3(1024), 0, stream>>>((const float4*)inputs, winner);
    run_chains<<<dim3(NIDS / 2), dim3(64), 0, stream>>>(inputs, K, R, bias, sinit, winner, table);
    finalize<<<dim3(B_ / 32), dim3(256), 0, stream>>>(inputs, K, R, bias, table, w1, b1, w2, b2, out);
}

// Round 5
// 106.395 us; speedup vs baseline: 2.8328x; 1.6189x over previous
//
#include <hip/hip_runtime.h>

#define B_   8192
#define T_   256
#define F_   18
#define U_   32
#define NIDS 1000

typedef float v2f  __attribute__((ext_vector_type(2)));
typedef float vf4  __attribute__((ext_vector_type(4)));
typedef v2f  f2a   __attribute__((may_alias));
typedef vf4  f4a   __attribute__((may_alias));
typedef float uf4  __attribute__((ext_vector_type(4), aligned(4), may_alias));
typedef float uf2  __attribute__((ext_vector_type(2), aligned(4), may_alias));

#define V2LO(v) __builtin_shufflevector(v, v, 0, 1)
#define V2HI(v) __builtin_shufflevector(v, v, 2, 3)

__device__ __forceinline__ float hsig(float x) {
    return fminf(fmaxf(fmaf(x, 0.2f, 0.5f), 0.f), 1.f);
}
__device__ __forceinline__ float ftanh(float x) {
    float g = __builtin_amdgcn_exp2f(2.885390081777927f * x);
    return 1.f - 2.f * __builtin_amdgcn_rcpf(g + 1.f);
}

// ---------------------------------------------------------------------------
// Phase 1a: coalesced float4 stream over the whole input; extract the id at
// element positions 18*m (only .x when 4v%18==0 or .z when 4v%18==16), stage
// in an LDS tile [t][b_local], then write a transposed compact u16 id array
// ids_t[t][8192] with full-64B-line stores. No atomics anywhere.
// ---------------------------------------------------------------------------
__global__ __launch_bounds__(1024) void extract_ids(
    const float4* __restrict__ in4, unsigned short* __restrict__ ids_t)
{
    __shared__ unsigned short tile[256][32];     // [t][b_local], 16 KB
    const int tid = threadIdx.x;
    const int blk = blockIdx.x;
    const int base = blk * 36864;                // 32 rows * 256 t * 18 / 4
#pragma unroll 9
    for (int k = 0; k < 36; ++k) {
        int v = k * 1024 + tid;
        float4 f = in4[base + v];
        unsigned e0 = (unsigned)v * 4u;
        unsigned rem = e0 % 18u;
        int j = (rem == 0u) ? 0 : (rem == 16u ? 2 : -1);
        if (j >= 0) {
            float fv = (j == 0) ? f.x : f.z;
            unsigned m = (e0 + (unsigned)j) / 18u;   // local ordinal: b_l*256+t
            int t = (int)(m & 255u);
            int bl = (int)(m >> 8);
            int id = (int)fv;
            id = id < 0 ? 0 : (id > NIDS - 1 ? NIDS - 1 : id);
            tile[t][bl] = (unsigned short)id;
        }
    }
    __syncthreads();
    const unsigned* tl = (const unsigned*)tile;  // index i = t*16 + p (2 ids)
    unsigned* dst = (unsigned*)ids_t;
#pragma unroll
    for (int i = tid; i < 4096; i += 1024) {
        int t = i >> 4, p = i & 15;
        dst[t * 4096 + blk * 16 + p] = tl[i];
    }
}

// ---------------------------------------------------------------------------
// Phase 1b: block per t. Read the contiguous 16KB id column, LDS atomicMax
// over 1000 entries (on-chip), write the winner column. Writes every entry,
// so no memset is needed.
// ---------------------------------------------------------------------------
__global__ __launch_bounds__(1024) void find_winners(
    const unsigned short* __restrict__ ids_t, int* __restrict__ winner)
{
    __shared__ int loc[NIDS];
    const int tid = threadIdx.x;
    const int t = blockIdx.x;
    for (int i = tid; i < NIDS; i += 1024) loc[i] = -1;
    __syncthreads();

    uint4 v = ((const uint4*)(ids_t + t * 8192))[tid];   // 8 ids, b=tid*8+e
    int b0 = tid * 8;
    atomicMax(&loc[v.x & 0xFFFFu], b0 + 0);
    atomicMax(&loc[v.x >> 16],     b0 + 1);
    atomicMax(&loc[v.y & 0xFFFFu], b0 + 2);
    atomicMax(&loc[v.y >> 16],     b0 + 3);
    atomicMax(&loc[v.z & 0xFFFFu], b0 + 4);
    atomicMax(&loc[v.z >> 16],     b0 + 5);
    atomicMax(&loc[v.w & 0xFFFFu], b0 + 6);
    atomicMax(&loc[v.w >> 16],     b0 + 7);
    __syncthreads();
    for (int i = tid; i < NIDS; i += 1024) winner[t * NIDS + i] = loc[i];
}

// ---------------------------------------------------------------------------
// Phase 2: one GRU step. h and p broadcast through LDS (same-wave DS ops are
// in-order -> no barriers). x-row + validity sentinel come from the chunked
// LDS buffer; the next step's x-dots are computed in the p round-trip shadow.
// Sentinel: vmask=1e6 added to dz -> z==1 -> h_new == h (skipped step).
// ---------------------------------------------------------------------------
__device__ __forceinline__ float do_step(
    const f4a* __restrict__ hb4, const f4a* __restrict__ pb4,
    float* __restrict__ pslot, float* __restrict__ hslot,
    float hown, float& dz, float& dr, float& dh,
    const v2f (&Uz)[16], const v2f (&Ur)[16], const v2f (&Uh)[16],
    const float* __restrict__ xnext,
    const v2f (&Kz)[9], const v2f (&Kr)[9], const v2f (&Kh)[9],
    float bz, float br, float bh)
{
    const float dhc = dh;
    v2f az0 = {dz, 0.f}, az1 = {0.f, 0.f};
    v2f ar0 = {dr, 0.f}, ar1 = {0.f, 0.f};
#pragma unroll
    for (int k = 0; k < 8; ++k) {
        vf4 hv = hb4[k];
        v2f lo = V2LO(hv), hi = V2HI(hv);
        az0 += lo * Uz[2*k];  az1 += hi * Uz[2*k+1];
        ar0 += lo * Ur[2*k];  ar1 += hi * Ur[2*k+1];
    }
    float z = hsig(az0.x + az0.y + az1.x + az1.y);
    float r = hsig(ar0.x + ar0.y + ar1.x + ar1.y);
    *pslot = r * hown;                       // ds_write p_j

    // filler while p write->read round-trips: next step's x-dots from LDS
    const f4a* xp = (const f4a*)xnext;
    vf4 x0 = xp[0], x1 = xp[1], x2 = xp[2], x3 = xp[3];
    v2f x4 = *(const f2a*)(xnext + 16);
    float vm = xnext[18];
    v2f nz = {bz, 0.f}, nr = {br, 0.f}, nh = {bh, 0.f};
    v2f xq[9] = {V2LO(x0), V2HI(x0), V2LO(x1), V2HI(x1),
                 V2LO(x2), V2HI(x2), V2LO(x3), V2HI(x3), x4};
#pragma unroll
    for (int q = 0; q < 9; ++q) {
        nz += xq[q] * Kz[q]; nr += xq[q] * Kr[q]; nh += xq[q] * Kh[q];
    }
    dz = nz.x + nz.y + vm; dr = nr.x + nr.y; dh = nh.x + nh.y;

    v2f ah0 = {dhc, 0.f}, ah1 = {0.f, 0.f};
#pragma unroll
    for (int k = 0; k < 8; ++k) {
        vf4 pv = pb4[k];
        ah0 += V2LO(pv) * Uh[2*k];  ah1 += V2HI(pv) * Uh[2*k+1];
    }
    float hh = ftanh(ah0.x + ah0.y + ah1.x + ah1.y);
    float hn = fmaf(z, hown - hh, hh);
    *hslot = hn;                             // ds_write h_j for next step
    return hn;
}

// ---------------------------------------------------------------------------
// Phase 2: 1000 chains, 2/wave, 1 wave/block. 16 chunks x 16 steps (t=255 is
// an automatic no-op via the sentinel). X-rows staged chunk-wise into LDS,
// double-buffered, loads issued one full chunk ahead (~16 steps ~ 6000cy).
// ---------------------------------------------------------------------------
__global__ __launch_bounds__(64, 1) void run_chains(
    const float* __restrict__ inputs, const float* __restrict__ K,
    const float* __restrict__ R, const float* __restrict__ bias,
    const float* __restrict__ sinit, const int* __restrict__ winner,
    float* __restrict__ table)
{
    __shared__ int wlds[2][256];
    __shared__ alignas(16) float xbuf[2][2][16][20];  // [buf][chain][row][18x+vm+pad]
    __shared__ alignas(16) float pbuf[2][32];
    __shared__ alignas(16) float hbuf[2][32];

    const int lane = threadIdx.x;
    const int c = lane >> 5, j = lane & 31;
    const int chain = blockIdx.x * 2 + c;

    // winner columns -> LDS (single wave: in-order DS, no barrier)
#pragma unroll
    for (int i = 0; i < 8; ++i) {
        int idx = i * 64 + lane;
        int cc = idx >> 8, t = idx & 255;
        wlds[cc][t] = (t < T_ - 1) ? winner[t * NIDS + blockIdx.x * 2 + cc] : -1;
    }
    float hinit = sinit[chain * U_ + j];
    hbuf[c][j] = hinit;
    float hown = hinit;

    v2f Uz[16], Ur[16], Uh[16];
#pragma unroll
    for (int k = 0; k < 16; ++k) {
        Uz[k] = (v2f){R[(2*k)*96 + j],      R[(2*k+1)*96 + j]};
        Ur[k] = (v2f){R[(2*k)*96 + 32 + j], R[(2*k+1)*96 + 32 + j]};
        Uh[k] = (v2f){R[(2*k)*96 + 64 + j], R[(2*k+1)*96 + 64 + j]};
    }
    v2f Kz[9], Kr[9], Kh[9];
#pragma unroll
    for (int q = 0; q < 9; ++q) {
        Kz[q] = (v2f){K[(2*q)*96 + j],      K[(2*q+1)*96 + j]};
        Kr[q] = (v2f){K[(2*q)*96 + 32 + j], K[(2*q+1)*96 + 32 + j]};
        Kh[q] = (v2f){K[(2*q)*96 + 64 + j], K[(2*q+1)*96 + 64 + j]};
    }
    const float bz = bias[j], br = bias[32 + j], bh = bias[64 + j];

    // staging role: 2 lanes per row; 32 rows = 2 chains x 16 steps
    const int rr = lane >> 1, pp = lane & 1;
    const int scc = rr >> 4, sidx = rr & 15;

    uf4 r0, r1; uf2 r2; float vmk = 0.f;

    auto issue_loads = [&](int ck) {
        int tt = ck * 16 + sidx;
        int w = wlds[scc][tt];
        vmk = (w < 0) ? 1e6f : 0.f;
        int wc = w < 0 ? 0 : w;
        const float* src = inputs + (size_t)(wc * 256 + tt) * 18;
        if (pp == 0) { r0 = *(const uf4*)(src);      r1 = *(const uf4*)(src + 4); }
        else         { r0 = *(const uf4*)(src + 8);  r1 = *(const uf4*)(src + 12);
                       r2 = *(const uf2*)(src + 16); }
    };
    auto write_buf = [&](int nb) {
        float* dst = &xbuf[nb][scc][sidx][0];
        if (pp == 0) { *(f4a*)(dst)      = (vf4)r0; *(f4a*)(dst + 4)  = (vf4)r1; }
        else         { *(f4a*)(dst + 8)  = (vf4)r0; *(f4a*)(dst + 12) = (vf4)r1;
                       *(f2a*)(dst + 16) = (v2f)r2; dst[18] = vmk; }
    };

    // prologue: chunk0 -> buf0; chunk1 loads left in flight
    issue_loads(0);
    write_buf(0);
    issue_loads(1);

    // initial dots for t=0 from buf0 row0
    float dz, dr, dh;
    {
        const float* x = &xbuf[0][c][0][0];
        const f4a* xp = (const f4a*)x;
        vf4 x0 = xp[0], x1 = xp[1], x2 = xp[2], x3 = xp[3];
        v2f x4 = *(const f2a*)(x + 16);
        float vm = x[18];
        v2f xq[9] = {V2LO(x0), V2HI(x0), V2LO(x1), V2HI(x1),
                     V2LO(x2), V2HI(x2), V2LO(x3), V2HI(x3), x4};
        v2f nz = {bz, 0.f}, nr = {br, 0.f}, nh = {bh, 0.f};
#pragma unroll
        for (int q = 0; q < 9; ++q) {
            nz += xq[q] * Kz[q]; nr += xq[q] * Kr[q]; nh += xq[q] * Kh[q];
        }
        dz = nz.x + nz.y + vm; dr = nr.x + nr.y; dh = nh.x + nh.y;
    }

    const f4a* hb4 = (const f4a*)hbuf[c];
    const f4a* pb4 = (const f4a*)pbuf[c];
    float* pslot = &pbuf[c][j];
    float* hslot = &hbuf[c][j];

    for (int i = 0; i < 16; ++i) {
        const float* bufc  = &xbuf[i & 1][c][0][0];
        const float* nbufc = &xbuf[(i + 1) & 1][c][0][0];
        for (int s = 0; s < 15; ++s) {
            hown = do_step(hb4, pb4, pslot, hslot, hown, dz, dr, dh,
                           Uz, Ur, Uh, bufc + (s + 1) * 20,
                           Kz, Kr, Kh, bz, br, bh);
        }
        if (i < 15) {
            write_buf((i + 1) & 1);
            if (i < 14) issue_loads(i + 2);
        }
        hown = do_step(hb4, pb4, pslot, hslot, hown, dz, dr, dh,
                       Uz, Ur, Uh, nbufc,
                       Kz, Kr, Kh, bz, br, bh);
    }

    table[chain * U_ + j] = hown;            // state entering t=255
}

// ---------------------------------------------------------------------------
// Phase 3: final step t=255 for all 8192 batch elements + MLP + sigmoid.
// ---------------------------------------------------------------------------
__device__ __forceinline__ float fin_gru_step(
    const float (&h)[16], float hown, const float (&xv)[9],
    const float (&Wz)[16], const float (&Wr)[16], const float (&Wh)[16],
    const float (&Kz)[9],  const float (&Kr)[9],  const float (&Kh)[9],
    float bz, float br, float bh, int kh)
{
    float az = 0.f, ar = 0.f;
#pragma unroll
    for (int kk = 0; kk < 16; ++kk) {
        az = fmaf(h[kk], Wz[kk], az);
        ar = fmaf(h[kk], Wr[kk], ar);
    }
#pragma unroll
    for (int q = 0; q < 9; ++q) {
        az = fmaf(xv[q], Kz[q], az);
        ar = fmaf(xv[q], Kr[q], ar);
    }
    az += __shfl_xor(az, 32, 64);
    ar += __shfl_xor(ar, 32, 64);
    float z = hsig(az + bz);
    float r = hsig(ar + br);
    float p = r * hown;
    float ah = 0.f;
#pragma unroll
    for (int kk = 0; kk < 16; ++kk) {
        float pkv = __shfl(p, kh * 16 + kk, 64);
        ah = fmaf(pkv, Wh[kk], ah);
    }
#pragma unroll
    for (int q = 0; q < 9; ++q) ah = fmaf(xv[q], Kh[q], ah);
    ah += __shfl_xor(ah, 32, 64);
    float hh = tanhf(ah + bh);
    return z * hown + (1.f - z) * hh;
}

__global__ __launch_bounds__(256) void finalize(
    const float* __restrict__ inputs, const float* __restrict__ K,
    const float* __restrict__ R, const float* __restrict__ bias,
    const float* __restrict__ table, const float* __restrict__ w1,
    const float* __restrict__ b1, const float* __restrict__ w2,
    const float* __restrict__ b2, float* __restrict__ out)
{
    int tid = threadIdx.x;
    int wv = tid >> 6, lane = tid & 63;
    int j = lane & 31, kh = lane >> 5;

    float Wz[16], Wr[16], Wh[16], w1c[16];
#pragma unroll
    for (int kk = 0; kk < 16; ++kk) {
        int k = kh * 16 + kk;
        Wz[kk]  = R[k * 96 + j];
        Wr[kk]  = R[k * 96 + 32 + j];
        Wh[kk]  = R[k * 96 + 64 + j];
        w1c[kk] = w1[k * 32 + j];
    }
    float Kz[9], Kr[9], Kh[9];
#pragma unroll
    for (int q = 0; q < 9; ++q) {
        int k = kh * 9 + q;
        Kz[q] = K[k * 96 + j];
        Kr[q] = K[k * 96 + 32 + j];
        Kh[q] = K[k * 96 + 64 + j];
    }
    float bz = bias[j], br = bias[32 + j], bh = bias[64 + j];
    float b1v = b1[j], w2v = w2[j], b2v = b2[0];

    int b0 = (blockIdx.x * 4 + wv) * 8;
    for (int bb = 0; bb < 8; ++bb) {
        int b = b0 + bb;
        const float* row = inputs + ((size_t)b * T_ + (T_ - 1)) * F_;
        int id = (int)row[0];
        float xv[9];
#pragma unroll
        for (int q = 0; q < 9; ++q) xv[q] = row[kh * 9 + q];
        float h[16], hown;
#pragma unroll
        for (int kk = 0; kk < 16; ++kk) h[kk] = table[id * U_ + kh * 16 + kk];
        hown = table[id * U_ + j];

        float hn = fin_gru_step(h, hown, xv, Wz, Wr, Wh, Kz, Kr, Kh, bz, br, bh, kh);
        float hrep[16];
#pragma unroll
        for (int kk = 0; kk < 16; ++kk) hrep[kk] = __shfl(hn, kh * 16 + kk, 64);

        float am = 0.f;
#pragma unroll
        for (int kk = 0; kk < 16; ++kk) am = fmaf(hrep[kk], w1c[kk], am);
        am += __shfl_xor(am, 32, 64);
        float hid = fmaxf(am + b1v, 0.f);
        float pr = (kh == 0) ? hid * w2v : 0.f;
#pragma unroll
        for (int s = 1; s < 64; s <<= 1) pr += __shfl_xor(pr, s, 64);
        if (lane == 0) out[b] = 1.f / (1.f + expf(-(pr + b2v)));
    }
}

// ---------------------------------------------------------------------------
extern "C" void kernel_launch(void* const* d_in, const int* in_sizes, int n_in,
                              void* d_out, int out_size, void* d_ws, size_t ws_size,
                              hipStream_t stream)
{
    const float* inputs = (const float*)d_in[0];
    const float* K      = (const float*)d_in[1];
    const float* R      = (const float*)d_in[2];
    const float* bias   = (const float*)d_in[3];
    const float* sinit  = (const float*)d_in[4];
    const float* w1     = (const float*)d_in[5];
    const float* b1     = (const float*)d_in[6];
    const float* w2     = (const float*)d_in[7];
    const float* b2     = (const float*)d_in[8];
    float* out = (float*)d_out;

    int*            winner = (int*)d_ws;                            // 1.0 MB
    float*          table  = (float*)((char*)d_ws + (1 << 20));     // 128 KB
    unsigned short* ids_t  = (unsigned short*)((char*)d_ws + (2 << 20)); // 4 MB

    extract_ids <<<dim3(256), dim3(1024), 0, stream>>>((const float4*)inputs, ids_t);
    find_winners<<<dim3(T_),  dim3(1024), 0, stream>>>(ids_t, winner);
    run_chains  <<<dim3(NIDS / 2), dim3(64), 0, stream>>>(inputs, K, R, bias, sinit, winner, table);
    finalize    <<<dim3(B_ / 32), dim3(256), 0, stream>>>(inputs, K, R, bias, table, w1, b1, w2, b2, out);
}